// Round 11
// baseline (101.332 us; speedup 1.0000x reference)
//
#include <hip/hip_runtime.h>

typedef float f32x4 __attribute__((ext_vector_type(4)));
typedef int   i32x4 __attribute__((ext_vector_type(4)));

// x: [1, 2049, 8192] f32 ; lambda: [1, 8192] f32
// out: [1, 1+2048+8192, 8192] f32
//   row 0           : center = lam*x0 - 0.5*lam*lower
//   rows 1..2048    : x[e]*lam
//   rows 2049..10240: one value per crossing column at row cumsum(has)-1, else 0

// K1: fused errs-scale + per-row-chunk abs partial sums (R10 form, neutral).
__global__ __launch_bounds__(256) void k_errs_partial(
    const float* __restrict__ x, const float* __restrict__ lam,
    float* __restrict__ out, float* __restrict__ partials,
    int N, int rowsPerChunk)
{
    const int col = (blockIdx.x * 256 + threadIdx.x) * 4;
    const int r0  = 1 + blockIdx.y * rowsPerChunk;
    const f32x4 l4 = *(const f32x4*)(lam + col);
    f32x4 acc = {0.f, 0.f, 0.f, 0.f};
    for (int rb = 0; rb < rowsPerChunk; rb += 8) {
        const float* xp = x + (size_t)(r0 + rb) * N + col;
        f32x4 v[8];
        #pragma unroll
        for (int j = 0; j < 8; ++j)
            v[j] = __builtin_nontemporal_load((const f32x4*)(xp + (size_t)j * N));
        float* op = out + (size_t)(r0 + rb) * N + col;
        #pragma unroll
        for (int j = 0; j < 8; ++j) {
            acc.x += fabsf(v[j].x); acc.y += fabsf(v[j].y);
            acc.z += fabsf(v[j].z); acc.w += fabsf(v[j].w);
            __builtin_nontemporal_store(v[j] * l4, (f32x4*)(op + (size_t)j * N));
        }
    }
    *(f32x4*)(partials + (size_t)blockIdx.y * N + col) = acc;
}

// K2: reduce partials per column, write center (out row 0), flags, vals.
__global__ __launch_bounds__(256) void k_stats(
    const float* __restrict__ x, const float* __restrict__ lam,
    const float* __restrict__ partials,
    float* __restrict__ out, float* __restrict__ vals, int* __restrict__ flags,
    int N, int P)
{
    const int n = blockIdx.x * 256 + threadIdx.x;
    float s = 0.f;
    for (int p = 0; p < P; ++p) s += partials[(size_t)p * N + n];
    const float x0 = x[n];          // row 0 of x
    const float l  = lam[n];
    const float lower = x0 - s;
    const float upper = x0 + s;
    out[n] = l * x0 - l * lower * 0.5f;          // center
    const bool has = (lower < 0.f) && (upper > 0.f);
    flags[n] = has ? 1 : 0;
    vals[n]  = has ? (-l * lower * 0.5f) : 0.f;
}

// K3: single-block scan of flags -> inverse map colOfRow[r] = column (or -1).
// Flag loads and -1 init vectorized to int4 (scalar stride-128B was uncoalesced).
__global__ __launch_bounds__(256) void k_scan(
    const int* __restrict__ flags, int* __restrict__ colOfRow, int N)
{
    __shared__ int waveSums[4];
    const int t    = threadIdx.x;
    const int base = t * 32;          // N/256 = 32 columns per thread
    int f[32];
    #pragma unroll
    for (int j = 0; j < 32; j += 4) {
        const i32x4 fv = *(const i32x4*)(flags + base + j);
        f[j] = fv.x; f[j+1] = fv.y; f[j+2] = fv.z; f[j+3] = fv.w;
    }
    int cnt = 0;
    #pragma unroll
    for (int i = 0; i < 32; ++i) cnt += f[i];
    const i32x4 m1 = {-1, -1, -1, -1};
    #pragma unroll
    for (int j = 0; j < 32; j += 4)
        *(i32x4*)(colOfRow + base + j) = m1;   // init; ordered vs scatter by barrier
    // inclusive shfl scan across the 64-lane wave
    const int lane = t & 63;
    const int wid  = t >> 6;
    int v = cnt;
    #pragma unroll
    for (int off = 1; off < 64; off <<= 1) {
        const int u = __shfl_up(v, off, 64);
        if (lane >= off) v += u;
    }
    if (lane == 63) waveSums[wid] = v;
    __syncthreads();                  // orders all inits before all scatters
    int wadd = 0;
    for (int w = 0; w < wid; ++w) wadd += waveSums[w];
    int run = v - cnt + wadd;         // exclusive prefix
    #pragma unroll
    for (int i = 0; i < 32; ++i) {
        if (f[i]) { colOfRow[run] = base + i; run += 1; }
    }
}

// K4: extra block, row-owned: 256 blocks (1/CU), each owns 32 contiguous rows
// = 1 MB linear footprint (the fewer/longer-streams pattern). All 32 rows'
// (c, val) pairs batch-preloaded up front so no dependent-load stall
// interrupts the store stream.
__global__ __launch_bounds__(256) void k_extra_rows(
    const float* __restrict__ vals, const int* __restrict__ colOfRow,
    float* __restrict__ outExtra, int N)
{
    const int t  = threadIdx.x;
    const int r0 = blockIdx.x * 32;
    int cA[32];
    #pragma unroll
    for (int j = 0; j < 32; j += 4) {
        const i32x4 cv = *(const i32x4*)(colOfRow + r0 + j);
        cA[j] = cv.x; cA[j+1] = cv.y; cA[j+2] = cv.z; cA[j+3] = cv.w;
    }
    float vA[32];
    #pragma unroll
    for (int j = 0; j < 32; ++j) vA[j] = (cA[j] >= 0) ? vals[cA[j]] : 0.f;

    #pragma unroll
    for (int j = 0; j < 32; ++j) {
        const int   c  = cA[j];
        const float vv = vA[j];
        float* rowp = outExtra + (size_t)(r0 + j) * N;
        #pragma unroll
        for (int s = 0; s < 8; ++s) {
            const int col = (s * 256 + t) * 4;
            f32x4 o;
            o.x = (c == col    ) ? vv : 0.f;
            o.y = (c == col + 1) ? vv : 0.f;
            o.z = (c == col + 2) ? vv : 0.f;
            o.w = (c == col + 3) ? vv : 0.f;
            __builtin_nontemporal_store(o, (f32x4*)(rowp + col));
        }
    }
}

extern "C" void kernel_launch(void* const* d_in, const int* in_sizes, int n_in,
                              void* d_out, int out_size, void* d_ws, size_t ws_size,
                              hipStream_t stream) {
    const float* x   = (const float*)d_in[0];
    const float* lam = (const float*)d_in[1];
    float* out = (float*)d_out;

    const int N  = in_sizes[1];            // 8192
    const int E1 = in_sizes[0] / N;        // 2049
    const int E  = E1 - 1;                 // 2048

    const int PBY = 32;                    // proven best (R5 vs R7)
    float* outExtra = out + (size_t)E1 * N;

    float* partials = (float*)d_ws;                     // [PBY][N]
    float* vals     = partials + (size_t)PBY * N;       // [N]
    int*   flags    = (int*)(vals + N);                 // [N]
    int*   colOfRow = flags + N;                        // [N]

    dim3 blk(256);

    dim3 g1(N / 1024, PBY);
    hipLaunchKernelGGL(k_errs_partial, g1, blk, 0, stream,
                       x, lam, out, partials, N, E / PBY);

    hipLaunchKernelGGL(k_stats, dim3(N / 256), blk, 0, stream,
                       x, lam, partials, out, vals, flags, N, PBY);

    hipLaunchKernelGGL(k_scan, dim3(1), blk, 0, stream,
                       flags, colOfRow, N);

    hipLaunchKernelGGL(k_extra_rows, dim3(N / 32), blk, 0, stream,
                       vals, colOfRow, outExtra, N);
}

// Round 12
// 86.461 us; speedup vs baseline: 1.1720x; 1.1720x over previous
//
#include <hip/hip_runtime.h>

typedef float f32x4 __attribute__((ext_vector_type(4)));

// x: [1, 2049, 8192] f32 ; lambda: [1, 8192] f32
// out: [1, 1+2048+8192, 8192] f32
//   row 0           : center = lam*x0 - 0.5*lam*lower
//   rows 1..2048    : x[e]*lam
//   rows 2049..10240: one value per crossing column at row cumsum(has)-1, else 0
//
// This round = byte-identical to the 96.1us R5 pipeline EXCEPT K4 stores are
// plain (not nontemporal). Single-variable A/B: does NT hurt linear store
// streams? (fillBufferAligned reaches 7 TB/s with plain stores.)

// K1: fused errs-scale + per-row-chunk abs partial sums.
// grid (8, 32) = 256 long-stream blocks (proven best geometry), NT kept.
__global__ __launch_bounds__(256) void k_errs_partial(
    const float* __restrict__ x, const float* __restrict__ lam,
    float* __restrict__ out, float* __restrict__ partials,
    int N, int rowsPerChunk)
{
    const int col = (blockIdx.x * 256 + threadIdx.x) * 4;
    const int r0  = 1 + blockIdx.y * rowsPerChunk;
    const f32x4 l4 = *(const f32x4*)(lam + col);
    f32x4 acc = {0.f, 0.f, 0.f, 0.f};
    #pragma unroll 4
    for (int r = r0; r < r0 + rowsPerChunk; ++r) {
        const f32x4 v = __builtin_nontemporal_load((const f32x4*)(x + (size_t)r * N + col));
        acc.x += fabsf(v.x); acc.y += fabsf(v.y); acc.z += fabsf(v.z); acc.w += fabsf(v.w);
        __builtin_nontemporal_store(v * l4, (f32x4*)(out + (size_t)r * N + col));
    }
    *(f32x4*)(partials + (size_t)blockIdx.y * N + col) = acc;
}

// K2: reduce partials per column, write center (out row 0), flags, vals.
__global__ __launch_bounds__(256) void k_stats(
    const float* __restrict__ x, const float* __restrict__ lam,
    const float* __restrict__ partials,
    float* __restrict__ out, float* __restrict__ vals, int* __restrict__ flags,
    int N, int P)
{
    const int n = blockIdx.x * 256 + threadIdx.x;
    float s = 0.f;
    for (int p = 0; p < P; ++p) s += partials[(size_t)p * N + n];
    const float x0 = x[n];          // row 0 of x
    const float l  = lam[n];
    const float lower = x0 - s;
    const float upper = x0 + s;
    out[n] = l * x0 - l * lower * 0.5f;          // center
    const bool has = (lower < 0.f) && (upper > 0.f);
    flags[n] = has ? 1 : 0;
    vals[n]  = has ? (-l * lower * 0.5f) : 0.f;
}

// K3: single-block scan of flags -> inverse map colOfRow[r] = column (or -1).
__global__ __launch_bounds__(256) void k_scan(
    const int* __restrict__ flags, int* __restrict__ colOfRow, int N)
{
    __shared__ int waveSums[4];
    const int t    = threadIdx.x;
    const int per  = N / 256;         // 32
    const int base = t * per;
    int f[32];
    int cnt = 0;
    #pragma unroll
    for (int i = 0; i < 32; ++i) {
        f[i] = flags[base + i];
        cnt += f[i];
        colOfRow[base + i] = -1;      // init; ordered vs scatter by barrier below
    }
    const int lane = t & 63;
    const int wid  = t >> 6;
    int v = cnt;
    #pragma unroll
    for (int off = 1; off < 64; off <<= 1) {
        const int u = __shfl_up(v, off, 64);
        if (lane >= off) v += u;
    }
    if (lane == 63) waveSums[wid] = v;
    __syncthreads();
    int wadd = 0;
    for (int w = 0; w < wid; ++w) wadd += waveSums[w];
    int run = v - cnt + wadd;         // exclusive prefix
    #pragma unroll
    for (int i = 0; i < 32; ++i) {
        if (f[i]) { colOfRow[run] = base + i; run += 1; }
    }
}

// K4: extra block, row-owned: block b fills rpb=8 contiguous rows (256 KB
// linear) injecting vals[colOfRow[r]]. PLAIN stores this round (was NT).
__global__ __launch_bounds__(256) void k_extra_rows(
    const float* __restrict__ vals, const int* __restrict__ colOfRow,
    float* __restrict__ outExtra, int N, int rowsPerBlock)
{
    const int t  = threadIdx.x;
    const int r0 = blockIdx.x * rowsPerBlock;
    for (int r = r0; r < r0 + rowsPerBlock; ++r) {
        const int   c  = colOfRow[r];             // broadcast scalar read
        const float vv = (c >= 0) ? vals[c] : 0.f;
        float* rowp = outExtra + (size_t)r * N;
        #pragma unroll
        for (int s = 0; s < 8; ++s) {
            const int col = (s * 256 + t) * 4;
            f32x4 o;
            o.x = (c == col    ) ? vv : 0.f;
            o.y = (c == col + 1) ? vv : 0.f;
            o.z = (c == col + 2) ? vv : 0.f;
            o.w = (c == col + 3) ? vv : 0.f;
            *(f32x4*)(rowp + col) = o;            // plain store (A/B vs NT)
        }
    }
}

extern "C" void kernel_launch(void* const* d_in, const int* in_sizes, int n_in,
                              void* d_out, int out_size, void* d_ws, size_t ws_size,
                              hipStream_t stream) {
    const float* x   = (const float*)d_in[0];
    const float* lam = (const float*)d_in[1];
    float* out = (float*)d_out;

    const int N  = in_sizes[1];            // 8192
    const int E1 = in_sizes[0] / N;        // 2049
    const int E  = E1 - 1;                 // 2048

    const int PBY = 32;                    // proven best (R5 vs R7)
    float* outExtra = out + (size_t)E1 * N;

    float* partials = (float*)d_ws;                     // [PBY][N]
    float* vals     = partials + (size_t)PBY * N;       // [N]
    int*   flags    = (int*)(vals + N);                 // [N]
    int*   colOfRow = flags + N;                        // [N]

    dim3 blk(256);

    dim3 g1(N / 1024, PBY);
    hipLaunchKernelGGL(k_errs_partial, g1, blk, 0, stream,
                       x, lam, out, partials, N, E / PBY);

    hipLaunchKernelGGL(k_stats, dim3(N / 256), blk, 0, stream,
                       x, lam, partials, out, vals, flags, N, PBY);

    hipLaunchKernelGGL(k_scan, dim3(1), blk, 0, stream,
                       flags, colOfRow, N);

    const int rpb = 8;                     // 1024 blocks, 256 KB linear per block
    hipLaunchKernelGGL(k_extra_rows, dim3(N / rpb), blk, 0, stream,
                       vals, colOfRow, outExtra, N, rpb);
}